// Round 19
// baseline (138.468 us; speedup 1.0000x reference)
//
#include <hip/hip_runtime.h>
#include <stdint.h>

// Problem constants
#define BB    16
#define DIMC  512
#define CHC   256
#define REDC  64
#define LL    32          // H == W == 32
#define NTOK  (BB*LL*LL)  // 16384 tokens

typedef unsigned short u16;
typedef unsigned char  u8;
typedef __attribute__((ext_vector_type(4))) float f32x4;
typedef __attribute__((ext_vector_type(2))) float f32x2;

__device__ __forceinline__ float bf2f(u16 u){
  union { unsigned int i; float f; } v; v.i = ((unsigned int)u) << 16; return v.f;
}
__device__ __forceinline__ u16 f2bf(float f){
  union { float f; unsigned int i; } v; v.f = f;
  unsigned int r = (v.i + 0x7FFFu + ((v.i >> 16) & 1u)) >> 16;
  return (u16)r;
}
__device__ __forceinline__ unsigned int pk4_fp8(float a, float b, float c, float d){
  unsigned int w = 0;
  w = __builtin_amdgcn_cvt_pk_fp8_f32(a, b, w, false);
  w = __builtin_amdgcn_cvt_pk_fp8_f32(c, d, w, true);
  return w;
}
__device__ __forceinline__ u8 f2fp8(float f){
  return (u8)(__builtin_amdgcn_cvt_pk_fp8_f32(f, f, 0, false) & 0xffu);
}

// async global->LDS, 16B per lane; LDS base must be wave-uniform.
__device__ __forceinline__ void gload16(const u8* g, u8* l) {
  __builtin_amdgcn_global_load_lds(
      (const __attribute__((address_space(1))) void*)g,
      (__attribute__((address_space(3))) void*)l, 16, 0, 0);
}

// ---------------------------------------------------------------------------
// K0: fused pre-pass. Blocks 0..511: weight transpose fp32 [K][N] -> fp8 [N][K].
// Blocks 512..8703: per-(b,ch) axis means -> g[br][b][c][l].
__global__ __launch_bounds__(256) void k_pre(const float* __restrict__ s1,
    u8* __restrict__ d1, const float* __restrict__ s2, u8* __restrict__ d2,
    const float* __restrict__ x, const float* __restrict__ pe_h,
    const float* __restrict__ pe_w, float* __restrict__ g)
{
  int tid = threadIdx.x;
  if (blockIdx.x < 512) {
    __shared__ float tf[64][65];
    int bid = blockIdx.x;
    const float* src; u8* dst; int K, N, n0, k0;
    if (bid < 256) { src = s1; dst = d1; K = 512;  N = 2048; n0 = (bid & 31) * 64; k0 = (bid >> 5) * 64; }
    else { bid -= 256; src = s2; dst = d2; K = 2048; N = 512; n0 = (bid & 7) * 64; k0 = (bid >> 3) * 64; }
    #pragma unroll
    for (int i = 0; i < 16; ++i) {
      int idx = i*256 + tid; int r = idx >> 6, c = idx & 63;
      tf[r][c] = src[(size_t)(k0 + r) * N + n0 + c];
    }
    __syncthreads();
    // writer: thread -> (c = tid>>2, 16-byte k-group gq = tid&3)
    int c = tid >> 2, gq = tid & 3;
    uint4 o;
    unsigned int* op = (unsigned int*)&o;
    #pragma unroll
    for (int d = 0; d < 4; ++d) {
      int j = gq*16 + d*4;
      op[d] = pk4_fp8(tf[j+0][c], tf[j+1][c], tf[j+2][c], tf[j+3][c]);
    }
    *(uint4*)(dst + (size_t)(n0 + c)*K + k0 + gq*16) = o;
    return;
  }
  // ---- means part ----
  int bc = blockIdx.x - 512;           // b*512 + ch
  int br = (bc & 511) >> 8, c = bc & 255;
  __shared__ float tt[32][33];
  const float* xp = x + (size_t)bc * 1024;
  float4 v = ((const float4*)xp)[tid];
  int h = tid >> 3, w4 = (tid & 7) * 4;
  tt[h][w4+0] = v.x; tt[h][w4+1] = v.y; tt[h][w4+2] = v.z; tt[h][w4+3] = v.w;
  __syncthreads();
  if (tid < 32) {
    float rs = 0.f;
    if (br == 0) {
      #pragma unroll
      for (int w = 0; w < 32; ++w) rs += tt[tid][w];     // mean over W (H-branch)
    } else {
      #pragma unroll
      for (int h2 = 0; h2 < 32; ++h2) rs += tt[h2][tid]; // mean over H (W-branch)
    }
    float tot = rs;
    #pragma unroll
    for (int off = 16; off >= 1; off >>= 1) tot += __shfl_xor(tot, off);
    const float* pe = (br == 0 ? pe_h : pe_w) + c*32;
    float pv = pe[tid];
    float pm = pv;
    #pragma unroll
    for (int off = 16; off >= 1; off >>= 1) pm += __shfl_xor(pm, off);
    int b = bc >> 9;
    float gv = rs * (1.f/32.f) + tot * (1.f/1024.f) + pv + pm * (1.f/32.f);
    g[((size_t)(br*BB + b)*256 + c)*32 + tid] = gv;
  }
}

// ---------------------------------------------------------------------------
// K1a: conv1 partials. grid 128 = (g32 = blk>>2 in [0,32), cq = blk&3).
__global__ __launch_bounds__(256) void k_gen1(const float* __restrict__ g,
    float* __restrict__ part, const float* __restrict__ g1w_h,
    const float* __restrict__ g1w_w)
{
  int blk = blockIdx.x; int g32 = blk >> 2, cq = blk & 3;
  int br = g32 >> 4;
  const float* g1w = br ? g1w_w : g1w_h;
  __shared__ float gs[64][34];   // padded: col 0 and 33 zero
  int tid = threadIdx.x;
  const float* gb = g + (size_t)g32 * 8192 + cq*64*32;
  if (tid < 64) { gs[tid][0] = 0.f; gs[tid][33] = 0.f; }
  #pragma unroll
  for (int it = 0; it < 8; ++it) {
    int idx = it*256 + tid;
    gs[idx >> 5][1 + (idx & 31)] = gb[idx];
  }
  __syncthreads();
  int r = tid >> 2, l0 = (tid & 3) * 8;
  float acc[8];
  #pragma unroll
  for (int j = 0; j < 8; ++j) acc[j] = 0.f;
  for (int c = 0; c < 64; ++c) {
    const float* wp = g1w + (r*256 + cq*64 + c)*3;
    float w0 = wp[0], w1 = wp[1], w2 = wp[2];
    float gv[10];
    #pragma unroll
    for (int q = 0; q < 10; ++q) gv[q] = gs[c][l0 + q];
    #pragma unroll
    for (int j = 0; j < 8; ++j) acc[j] += w0*gv[j] + w1*gv[j+1] + w2*gv[j+2];
  }
  float* po = part + (size_t)blk*2048 + r*32 + l0;
  #pragma unroll
  for (int j = 0; j < 8; ++j) po[j] = acc[j];
}

// ---------------------------------------------------------------------------
// K1b: conv2 partial-channel blocks. grid 128 = (g32 = blk>>2, cq = blk&3).
__global__ __launch_bounds__(256) void k_gen2(const float* __restrict__ part,
    float* __restrict__ a2buf, float* __restrict__ sred,
    const float* bng_h, const float* bnb_h, const float* bnrm_h, const float* bnrv_h,
    const float* g2w_h, const float* bng_w, const float* bnb_w,
    const float* bnrm_w, const float* bnrv_w, const float* g2w_w)
{
  int blk = blockIdx.x; int g32 = blk >> 2, cq = blk & 3;
  int br = g32 >> 4;
  const float* bng  = br ? bng_w  : bng_h;
  const float* bnb  = br ? bnb_w  : bnb_h;
  const float* bnrm = br ? bnrm_w : bnrm_h;
  const float* bnrv = br ? bnrv_w : bnrv_h;
  const float* g2w  = br ? g2w_w  : g2w_h;

  __shared__ float h1[64][34];
  __shared__ float wlds[64*195];   // stride 195: 195%32=3 -> 16 cl conflict-free
  __shared__ float red[8];
  int tid = threadIdx.x;

  // (a) phase A: reduce 4 partials -> BN -> hardswish -> h1
  {
    int r = tid >> 2, l0 = (tid & 3) * 8;
    if ((tid & 3) == 0) { h1[r][0] = 0.f; h1[r][33] = 0.f; }
    const float* p0 = part + (size_t)(g32*4 + 0)*2048 + r*32 + l0;
    const float* p1 = part + (size_t)(g32*4 + 1)*2048 + r*32 + l0;
    const float* p2 = part + (size_t)(g32*4 + 2)*2048 + r*32 + l0;
    const float* p3 = part + (size_t)(g32*4 + 3)*2048 + r*32 + l0;
    float sc = bng[r] * rsqrtf(bnrv[r] + 1e-5f);
    float sh = bnb[r] - bnrm[r] * sc;
    #pragma unroll
    for (int j = 0; j < 8; ++j) {
      float v2 = (p0[j] + p1[j] + p2[j] + p3[j])*sc + sh;            // BN
      float hs = v2 * fminf(fmaxf(v2 + 3.f, 0.f), 6.f) * (1.f/6.f);  // hardswish
      h1[r][1 + l0 + j] = hs;
    }
  }
  // (b) stage g2w slice (c in [cq*64, cq*64+64)): 12288 contiguous floats
  {
    const float* wsrc = g2w + cq*12288;
    #pragma unroll
    for (int it = 0; it < 48; ++it) {
      int i = it*256 + tid;
      int cl = i / 192;
      int rem = i - cl*192;
      wlds[cl*195 + rem] = wsrc[i];
    }
  }
  __syncthreads();

  // (c) conv2: thread = (cl = tid>>2, l-octet = tid&3)
  int cl = tid >> 2, l0 = (tid & 3) * 8;
  const float* wp = &wlds[cl*195];
  float a2[8];
  #pragma unroll
  for (int j = 0; j < 8; ++j) a2[j] = 0.f;
  for (int r = 0; r < 64; ++r) {
    float w0 = wp[r*3+0], w1 = wp[r*3+1], w2 = wp[r*3+2];
    float hv[10];
    #pragma unroll
    for (int q = 0; q < 10; ++q) hv[q] = h1[r][l0 + q];
    #pragma unroll
    for (int j = 0; j < 8; ++j) a2[j] += w0*hv[j] + w1*hv[j+1] + w2*hv[j+2];
  }
  // (d) block partial moments + a2 out
  float s = 0.f, sq = 0.f;
  #pragma unroll
  for (int j = 0; j < 8; ++j) { s += a2[j]; sq += a2[j]*a2[j]; }
  #pragma unroll
  for (int off = 32; off >= 1; off >>= 1) { s += __shfl_xor(s, off); sq += __shfl_xor(sq, off); }
  if ((tid & 63) == 0) { red[(tid >> 6)*2] = s; red[(tid >> 6)*2+1] = sq; }
  __syncthreads();
  if (tid == 0) {
    sred[blk*2+0] = red[0] + red[2] + red[4] + red[6];
    sred[blk*2+1] = red[1] + red[3] + red[5] + red[7];
  }
  float* ao = a2buf + (size_t)(g32*256 + cq*64 + cl)*32 + l0;
  #pragma unroll
  for (int j = 0; j < 8; ++j) ao[j] = a2[j];
}

// ---------------------------------------------------------------------------
// K3: circulant apply per (b,ch) with INLINE filter-norm. Writes ybr FP8.
// xs[32][68]: cols 32..63 duplicate 0..31 -> W-branch indexes w4+j+k directly
// (no &31); H-branch float4 reads cols < 32 unchanged.
__global__ __launch_bounds__(256) void k_circ(const float* __restrict__ x,
    const float* __restrict__ pe_h, const float* __restrict__ pe_w,
    const float* __restrict__ bias_h, const float* __restrict__ bias_w,
    const float* __restrict__ a2buf, const float* __restrict__ sred,
    const float* __restrict__ fns_h, const float* __restrict__ fnm_h,
    const float* __restrict__ fns_w, const float* __restrict__ fnm_w,
    u8* __restrict__ ybr)
{
  int bc = blockIdx.x;
  int b = bc >> 9, ch = bc & 511, br = ch >> 8, c = ch & 255;
  __shared__ float xs[32][68];
  __shared__ float ww[32];
  int tid = threadIdx.x;
  const float* xp = x + (size_t)bc * 1024;
  float4 v = ((const float4*)xp)[tid];
  int h = tid >> 3, w4 = (tid & 7) * 4;
  float4 sv;
  if (br == 0) {
    float p = pe_h[c*32 + h];
    sv.x = v.x + p; sv.y = v.y + p; sv.z = v.z + p; sv.w = v.w + p;
  } else {
    float4 pw = *(const float4*)(pe_w + c*32 + w4);
    sv.x = v.x + pw.x; sv.y = v.y + pw.y; sv.z = v.z + pw.z; sv.w = v.w + pw.w;
  }
  *(float4*)&xs[h][w4]      = sv;
  *(float4*)&xs[h][w4 + 32] = sv;     // duplicated columns for wrap-free reads
  if (tid < 32) {
    int g32v = br*BB + b;
    float S  = sred[g32v*8+0] + sred[g32v*8+2] + sred[g32v*8+4] + sred[g32v*8+6];
    float SQ = sred[g32v*8+1] + sred[g32v*8+3] + sred[g32v*8+5] + sred[g32v*8+7];
    float u   = S * (1.f/8192.f);
    float var = SQ * (1.f/8192.f) - u*u;
    float inv = rsqrtf(var + 1e-6f);
    const float* fns = br ? fns_w : fns_h;
    const float* fnm = br ? fnm_w : fnm_h;
    float av = a2buf[((size_t)g32v*256 + c)*32 + tid];
    ww[tid] = (av - u)*inv*fns[c*32 + tid] + fnm[c*32 + tid];
  }
  __syncthreads();
  float bias = (br ? bias_w : bias_h)[c];
  int i = tid >> 3;
  float o0 = bias, o1 = bias, o2 = bias, o3 = bias;
  if (br == 0) {
    #pragma unroll
    for (int k = 0; k < 32; ++k) {
      float wk = ww[k]; int rr = (i + k) & 31;
      float4 xv = *(const float4*)&xs[rr][w4];
      o0 += wk*xv.x; o1 += wk*xv.y; o2 += wk*xv.z; o3 += wk*xv.w;
    }
  } else {
    #pragma unroll
    for (int k = 0; k < 32; ++k) {
      float wk = ww[k];
      o0 += wk*xs[i][w4+0+k]; o1 += wk*xs[i][w4+1+k];
      o2 += wk*xs[i][w4+2+k]; o3 += wk*xs[i][w4+3+k];
    }
  }
  ((unsigned int*)(ybr + (size_t)bc * 1024))[tid] = pk4_fp8(o0, o1, o2, o3);
}

// ---------------------------------------------------------------------------
// K4: transpose (b,ch,h,w)->token-major + LayerNorm + fp8 pack. A8 [token][512].
// ybr input is FP8 (decoded via cvt_pk_f32_fp8).
__global__ __launch_bounds__(256) void k_ln(const u8* __restrict__ ybr,
    const float* __restrict__ ln_w, const float* __restrict__ ln_b,
    u8* __restrict__ A8)
{
  int bh = blockIdx.x; int b = bh >> 5, h = bh & 31;
  __shared__ float ys[512][33];
  __shared__ float ps[8][32], pq[8][32];
  __shared__ float mus[32], rstds[32];
  __shared__ float lw[512], lb[512];
  int tid = threadIdx.x;
  lw[tid]       = ln_w[tid];       lb[tid]       = ln_b[tid];
  lw[tid + 256] = ln_w[tid + 256]; lb[tid + 256] = ln_b[tid + 256];
  #pragma unroll
  for (int it = 0; it < 16; ++it) {
    int vid = it*256 + tid; int ch = vid >> 3; int w4 = (vid & 7) * 4;
    unsigned int v = *(const unsigned int*)(ybr + (size_t)(b*512 + ch)*1024 + h*32 + w4);
    f32x2 lo = __builtin_amdgcn_cvt_pk_f32_fp8(v, false);
    f32x2 hi = __builtin_amdgcn_cvt_pk_f32_fp8(v, true);
    ys[ch][w4+0] = lo.x; ys[ch][w4+1] = lo.y;
    ys[ch][w4+2] = hi.x; ys[ch][w4+3] = hi.y;
  }
  __syncthreads();
  int w = tid & 31, gq = tid >> 5;
  float s = 0.f, sq = 0.f;
  for (int cc = gq*64; cc < gq*64 + 64; ++cc) { float vv = ys[cc][w]; s += vv; sq += vv*vv; }
  ps[gq][w] = s; pq[gq][w] = sq;
  __syncthreads();
  if (tid < 32) {
    float S = 0.f, SQ = 0.f;
    #pragma unroll
    for (int q = 0; q < 8; ++q) { S += ps[q][tid]; SQ += pq[q][tid]; }
    float mu = S * (1.f/512.f);
    float var = SQ * (1.f/512.f) - mu*mu;
    mus[tid] = mu; rstds[tid] = rsqrtf(var + 1e-6f);
  }
  __syncthreads();
  u8* Arow = A8 + (size_t)(b*1024 + h*32) * 512;
  #pragma unroll
  for (int it = 0; it < 16; ++it) {
    int idx = it*256 + tid;                 // 4096 dword groups
    int w2 = idx >> 7, cg = idx & 127; int cc = cg*4;
    float mu = mus[w2], rs2 = rstds[w2];
    float v0 = (ys[cc+0][w2] - mu) * rs2 * lw[cc+0] + lb[cc+0];
    float v1 = (ys[cc+1][w2] - mu) * rs2 * lw[cc+1] + lb[cc+1];
    float v2 = (ys[cc+2][w2] - mu) * rs2 * lw[cc+2] + lb[cc+2];
    float v3 = (ys[cc+3][w2] - mu) * rs2 * lw[cc+3] + lb[cc+3];
    ((unsigned int*)(Arow + (size_t)w2*512))[cg] = pk4_fp8(v0, v1, v2, v3);
  }
}

// ---------------------------------------------------------------------------
// K5/K6: fp8 MFMA GEMM (R13 core). 1-D grid with XCD-AWARE TEMPORAL SWIZZLE
// (round-robin dispatch model proven by R16/R17 counters):
//   x = lin&7 (XCD), j = lin>>3, n = j%NB, m = (j/NB)*8 + x.
// Depth-2 prefetch, 3 LDS slots (48 KB, 3 blocks/CU). vmcnt(4)/(2)/(0).
// Chunk swizzle swz(r) = ((r>>1)^(r>>3))&3 on BOTH source and read.
// EPI=1: LDS-transpose epilogue + hard-sigmoid GELU. EPI=2: float4 residual.
template<int EPI, int NB>
__global__ __launch_bounds__(512, 6) void k_gemm(
    const u8* __restrict__ A, const u8* __restrict__ BT,
    void* __restrict__ outv, const float* __restrict__ xin,
    const float* __restrict__ bias, const float* __restrict__ gamma,
    int K, int N, int a_row_off, int out_row_off)
{
  __shared__ u8 As[3][8192];
  __shared__ u8 Bs[3][8192];
  int tid = threadIdx.x;
  int lin = blockIdx.x;
  int mblocks = gridDim.x / NB;
  int m0, n0;
  if ((gridDim.x & 7) == 0 && (mblocks & 7) == 0) {
    int xcd = lin & 7, j = lin >> 3;
    n0 = (j % NB) * 128;
    m0 = ((j / NB) * 8 + xcd) * 128;
  } else {
    m0 = (lin % mblocks) * 128;          // m-fast identity fallback
    n0 = (lin / mblocks) * 128;
  }
  int lane = tid & 63, wid = tid >> 6;
  int wr = wid >> 1, wc = wid & 1;          // wave tile: rows wr*32.., cols wc*64..
  f32x4 acc[2][4];
  #pragma unroll
  for (int mi = 0; mi < 2; ++mi)
    #pragma unroll
    for (int ni = 0; ni < 4; ++ni) acc[mi][ni] = (f32x4){0.f,0.f,0.f,0.f};

  // staging: tile = 128 rows x 64 B; wave u covers rows 16u..16u+15.
  // lane l -> row 16u + (l>>2), 16B chunk (l&3) ^ swz(row).
  int rloc = (wid << 4) + (lane >> 2);
  int swzr = ((rloc >> 1) ^ (rloc >> 3)) & 3;
  int cp   = (lane & 3) ^ swzr;
  const u8* aSrc = A  + (size_t)(a_row_off + m0 + rloc)*K + cp*16;
  const u8* bSrc = BT + (size_t)(n0 + rloc)*K + cp*16;
  int ldsOff = wid * 1024;                  // wave-uniform byte base

  auto stage = [&](int t, int slot) {
    int k0 = t << 6;
    gload16(aSrc + k0, &As[slot][ldsOff]);
    gload16(bSrc + k0, &Bs[slot][ldsOff]);
  };
  // b64 fragment read: logical bytes [row][kk + q*8 .. +8]
  auto lds8 = [&](const u8* base, int row, int kk, int q) -> long {
    int j = (kk >> 4) + (q >> 1);
    int sz = ((row >> 1) ^ (row >> 3)) & 3;
    int byte = row*64 + ((j ^ sz) << 4) + ((q & 1) << 3);
    return *(const long*)(base + byte);
  };

  int nt = K >> 6;
  stage(0, 0);                              // prologue: depth-2
  stage(1, 1);

  int sr = 0;                               // slot of tile t
  for (int t = 0; t < nt; ++t) {
    if (t + 2 < nt) {
      int sw = (sr == 0) ? 2 : sr - 1;      // (t+2)%3 == (t-1)%3
      stage(t + 2, sw);
      asm volatile("s_waitcnt vmcnt(4)" ::: "memory");   // tile t landed; t+1,t+2 in flight
    } else if (t + 1 < nt) {
      asm volatile("s_waitcnt vmcnt(2)" ::: "memory");   // tile t landed; t+1 in flight
    } else {
      asm volatile("s_waitcnt vmcnt(0)" ::: "memory");
    }
    __builtin_amdgcn_s_barrier();                        // tile t collectively valid
    const u8* Ar = &As[sr][0];
    const u8* Br = &Bs[sr][0];
    int q = lane >> 4;
    #pragma unroll
    for (int kk = 0; kk < 64; kk += 32) {
      long af[2], bfr[4];
      #pragma unroll
      for (int mi = 0; mi < 2; ++mi)
        af[mi] = lds8(Ar, wr*32 + mi*16 + (lane & 15), kk, q);
      #pragma unroll
      for (int ni = 0; ni < 4; ++ni)
        bfr[ni] = lds8(Br, wc*64 + ni*16 + (lane & 15), kk, q);
      #pragma unroll
      for (int mi = 0; mi < 2; ++mi)
        #pragma unroll
        for (int ni = 0; ni < 4; ++ni)
          acc[mi][ni] = __builtin_amdgcn_mfma_f32_16x16x32_fp8_fp8(af[mi], bfr[ni], acc[mi][ni], 0, 0, 0);
    }
    __builtin_amdgcn_s_barrier();   // protect the slot the next stage overwrites
    sr = (sr == 2) ? 0 : sr + 1;
  }

  // ---------------- epilogue ----------------
  // D layout: col = lane&15 (n), row = (lane>>4)*4 + r (m), per (mi,ni) frag.
  if (EPI == 1) {
    // LDS-transpose epilogue: wave region 32 rows x 64 cols, row stride 80B.
    __builtin_amdgcn_s_barrier();           // all waves done reading As/Bs
    u8* eb = &As[0][0] + wid * 2560;        // 8 waves x 2560B = 20KB <= 24KB
    #pragma unroll
    for (int mi = 0; mi < 2; ++mi) {
      #pragma unroll
      for (int ni = 0; ni < 4; ++ni) {
        int n = n0 + wc*64 + ni*16 + (lane & 15);
        float bn = bias[n];
        int col = ni*16 + (lane & 15);
        #pragma unroll
        for (int r = 0; r < 4; ++r) {
          int lrow = mi*16 + (lane >> 4)*4 + r;
          float v = acc[mi][ni][r] + bn;
          // hard-sigmoid GELU: v * clamp(0.2837v + 0.5, 0, 1)  (exp-free)
          float hs = fminf(fmaxf(0.2837f * v + 0.5f, 0.f), 1.f);
          eb[lrow*80 + col] = f2fp8(v * hs);
        }
      }
    }
    asm volatile("s_waitcnt lgkmcnt(0)" ::: "memory");  // own-region writes done
    int lr = lane >> 1, h2 = lane & 1;
    uint4 w0 = *(const uint4*)(eb + lr*80 + h2*32);
    uint4 w1 = *(const uint4*)(eb + lr*80 + h2*32 + 16);
    u8* zrow = (u8*)outv + (size_t)(m0 + wr*32 + lr)*N + n0 + wc*64 + h2*32;
    *(uint4*)(zrow)      = w0;
    *(uint4*)(zrow + 16) = w1;
  } else {
    #pragma unroll
    for (int mi = 0; mi < 2; ++mi) {
      #pragma unroll
      for (int ni = 0; ni < 4; ++ni) {
        int n = n0 + wc*64 + ni*16 + (lane & 15);
        float bn = bias[n];
        float gm = gamma[n];
        int mb = m0 + wr*32 + mi*16 + (lane >> 4)*4;    // 4-aligned token base
        int mg = out_row_off + mb;
        int bb = mg >> 10, hh = (mg >> 5) & 31, wv = mg & 31;
        size_t oi = ((size_t)(bb*512 + n))*1024 + hh*32 + wv;
        float4 xv = *(const float4*)(xin + oi);
        float4 ov;
        ov.x = xv.x + gm * (acc[mi][ni][0] + bn);
        ov.y = xv.y + gm * (acc[mi][ni][1] + bn);
        ov.z = xv.z + gm * (acc[mi][ni][2] + bn);
        ov.w = xv.w + gm * (acc[mi][ni][3] + bn);
        *(float4*)((float*)outv + oi) = ov;
      }
    }
  }
}

// ---------------------------------------------------------------------------
extern "C" void kernel_launch(void* const* d_in, const int* in_sizes, int n_in,
                              void* d_out, int out_size, void* d_ws, size_t ws_size,
                              hipStream_t stream)
{
  const float* x      = (const float*)d_in[0];
  const float* pe_h   = (const float*)d_in[1];
  const float* g1w_h  = (const float*)d_in[2];
  const float* bng_h  = (const float*)d_in[3];
  const float* bnb_h  = (const float*)d_in[4];
  const float* bnrm_h = (const float*)d_in[5];
  const float* bnrv_h = (const float*)d_in[6];
  const float* g2w_h  = (const float*)d_in[7];
  const float* fns_h  = (const float*)d_in[8];
  const float* fnm_h  = (const float*)d_in[9];
  const float* bias_h = (const float*)d_in[10];
  const float* pe_w   = (const float*)d_in[11];
  const float* g1w_w  = (const float*)d_in[12];
  const float* bng_w  = (const float*)d_in[13];
  const float* bnb_w  = (const float*)d_in[14];
  const float* bnrm_w = (const float*)d_in[15];
  const float* bnrv_w = (const float*)d_in[16];
  const float* g2w_w  = (const float*)d_in[17];
  const float* fns_w  = (const float*)d_in[18];
  const float* fnm_w  = (const float*)d_in[19];
  const float* bias_w = (const float*)d_in[20];
  const float* ln_w   = (const float*)d_in[21];
  const float* ln_b   = (const float*)d_in[22];
  const float* pw1w   = (const float*)d_in[23];
  const float* pw1b   = (const float*)d_in[24];
  const float* pw2w   = (const float*)d_in[25];
  const float* pw2b   = (const float*)d_in[26];
  const float* gamma  = (const float*)d_in[27];
  float* out = (float*)d_out;

  char* ws = (char*)d_ws;
  size_t off = 0;
  auto carve = [&](size_t bytes) -> void* {
    void* p = ws + off; off += (bytes + 255) & ~(size_t)255; return p;
  };
  float* g    = (float*)carve((size_t)2*BB*256*32*4);   // 1 MB
  float* part = (float*)carve((size_t)128*2048*4);      // 1 MB conv1 partials
  float* a2b  = (float*)carve((size_t)32*256*32*4);     // 1 MB conv2 pre-norm
  float* sred = (float*)carve((size_t)128*2*4);         // block moments
  u8* BT1     = (u8*)carve((size_t)2048*512);           // 1 MB fp8
  u8* BT2     = (u8*)carve((size_t)512*2048);           // 1 MB fp8
  u8* Abuf    = (u8*)carve((size_t)NTOK*512);           // 8.4 MB fp8
  size_t tail = off;                                    // ybr / Z share this region
  u8* ybr = (u8*)(ws + tail);                           // 8.4 MB fp8 branch out
  u8* Z   = (u8*)(ws + tail);                           // Z overwrites dead ybr
  size_t ybr_bytes = (size_t)NTOK*512;                  // 8.4 MB
  int nch = 1;                                          // chunk M so Z fits in ws
  while (nch < 16) {
    size_t zb = ((size_t)NTOK/nch)*2048;                // fp8 Z
    size_t need = tail + (zb > ybr_bytes ? zb : ybr_bytes);
    if (need <= ws_size) break;
    nch *= 2;
  }

  k_pre<<<512 + BB*512, 256, 0, stream>>>(pw1w, BT1, pw2w, BT2, x, pe_h, pe_w, g);
  k_gen1<<<128, 256, 0, stream>>>(g, part, g1w_h, g1w_w);
  k_gen2<<<128, 256, 0, stream>>>(part, a2b, sred,
      bng_h, bnb_h, bnrm_h, bnrv_h, g2w_h,
      bng_w, bnb_w, bnrm_w, bnrv_w, g2w_w);
  k_circ<<<BB*512, 256, 0, stream>>>(x, pe_h, pe_w, bias_h, bias_w,
      a2b, sred, fns_h, fnm_h, fns_w, fnm_w, ybr);
  k_ln<<<BB*LL, 256, 0, stream>>>(ybr, ln_w, ln_b, Abuf);

  int Mc = NTOK / nch;
  for (int ci = 0; ci < nch; ++ci) {
    int moff = ci * Mc;
    k_gemm<1,16><<<(Mc/128)*16, 512, 0, stream>>>(
        Abuf, BT1, Z, nullptr, pw1b, nullptr, 512, 2048, moff, 0);
    k_gemm<2,4><<<(Mc/128)*4, 512, 0, stream>>>(
        Z, BT2, out, x, pw2b, gamma, 2048, 512, 0, moff);
  }
}

// Round 20
// 135.721 us; speedup vs baseline: 1.0202x; 1.0202x over previous
//
#include <hip/hip_runtime.h>
#include <stdint.h>

// Problem constants
#define BB    16
#define DIMC  512
#define CHC   256
#define REDC  64
#define LL    32          // H == W == 32
#define NTOK  (BB*LL*LL)  // 16384 tokens

typedef unsigned short u16;
typedef unsigned char  u8;
typedef __attribute__((ext_vector_type(4))) float f32x4;

__device__ __forceinline__ float bf2f(u16 u){
  union { unsigned int i; float f; } v; v.i = ((unsigned int)u) << 16; return v.f;
}
__device__ __forceinline__ u16 f2bf(float f){
  union { float f; unsigned int i; } v; v.f = f;
  unsigned int r = (v.i + 0x7FFFu + ((v.i >> 16) & 1u)) >> 16;
  return (u16)r;
}
__device__ __forceinline__ unsigned int pk4_fp8(float a, float b, float c, float d){
  unsigned int w = 0;
  w = __builtin_amdgcn_cvt_pk_fp8_f32(a, b, w, false);
  w = __builtin_amdgcn_cvt_pk_fp8_f32(c, d, w, true);
  return w;
}
__device__ __forceinline__ u8 f2fp8(float f){
  return (u8)(__builtin_amdgcn_cvt_pk_fp8_f32(f, f, 0, false) & 0xffu);
}

// async global->LDS, 16B per lane; LDS base must be wave-uniform.
__device__ __forceinline__ void gload16(const u8* g, u8* l) {
  __builtin_amdgcn_global_load_lds(
      (const __attribute__((address_space(1))) void*)g,
      (__attribute__((address_space(3))) void*)l, 16, 0, 0);
}

// ---------------------------------------------------------------------------
// K0: fused pre-pass. Blocks 0..511: weight transpose fp32 [K][N] -> fp8 [N][K].
// Blocks 512..8703: per-(b,ch) axis means -> g[br][b][c][l].
__global__ __launch_bounds__(256) void k_pre(const float* __restrict__ s1,
    u8* __restrict__ d1, const float* __restrict__ s2, u8* __restrict__ d2,
    const float* __restrict__ x, const float* __restrict__ pe_h,
    const float* __restrict__ pe_w, float* __restrict__ g)
{
  int tid = threadIdx.x;
  if (blockIdx.x < 512) {
    __shared__ float tf[64][65];
    int bid = blockIdx.x;
    const float* src; u8* dst; int K, N, n0, k0;
    if (bid < 256) { src = s1; dst = d1; K = 512;  N = 2048; n0 = (bid & 31) * 64; k0 = (bid >> 5) * 64; }
    else { bid -= 256; src = s2; dst = d2; K = 2048; N = 512; n0 = (bid & 7) * 64; k0 = (bid >> 3) * 64; }
    #pragma unroll
    for (int i = 0; i < 16; ++i) {
      int idx = i*256 + tid; int r = idx >> 6, c = idx & 63;
      tf[r][c] = src[(size_t)(k0 + r) * N + n0 + c];
    }
    __syncthreads();
    // writer: thread -> (c = tid>>2, 16-byte k-group gq = tid&3)
    int c = tid >> 2, gq = tid & 3;
    uint4 o;
    unsigned int* op = (unsigned int*)&o;
    #pragma unroll
    for (int d = 0; d < 4; ++d) {
      int j = gq*16 + d*4;
      op[d] = pk4_fp8(tf[j+0][c], tf[j+1][c], tf[j+2][c], tf[j+3][c]);
    }
    *(uint4*)(dst + (size_t)(n0 + c)*K + k0 + gq*16) = o;
    return;
  }
  // ---- means part ----
  int bc = blockIdx.x - 512;           // b*512 + ch
  int br = (bc & 511) >> 8, c = bc & 255;
  __shared__ float tt[32][33];
  const float* xp = x + (size_t)bc * 1024;
  float4 v = ((const float4*)xp)[tid];
  int h = tid >> 3, w4 = (tid & 7) * 4;
  tt[h][w4+0] = v.x; tt[h][w4+1] = v.y; tt[h][w4+2] = v.z; tt[h][w4+3] = v.w;
  __syncthreads();
  if (tid < 32) {
    float rs = 0.f;
    if (br == 0) {
      #pragma unroll
      for (int w = 0; w < 32; ++w) rs += tt[tid][w];     // mean over W (H-branch)
    } else {
      #pragma unroll
      for (int h2 = 0; h2 < 32; ++h2) rs += tt[h2][tid]; // mean over H (W-branch)
    }
    float tot = rs;
    #pragma unroll
    for (int off = 16; off >= 1; off >>= 1) tot += __shfl_xor(tot, off);
    const float* pe = (br == 0 ? pe_h : pe_w) + c*32;
    float pv = pe[tid];
    float pm = pv;
    #pragma unroll
    for (int off = 16; off >= 1; off >>= 1) pm += __shfl_xor(pm, off);
    int b = bc >> 9;
    float gv = rs * (1.f/32.f) + tot * (1.f/1024.f) + pv + pm * (1.f/32.f);
    g[((size_t)(br*BB + b)*256 + c)*32 + tid] = gv;
  }
}

// ---------------------------------------------------------------------------
// K1a: conv1 partials. grid 128 = (g32 = blk>>2 in [0,32), cq = blk&3).
__global__ __launch_bounds__(256) void k_gen1(const float* __restrict__ g,
    float* __restrict__ part, const float* __restrict__ g1w_h,
    const float* __restrict__ g1w_w)
{
  int blk = blockIdx.x; int g32 = blk >> 2, cq = blk & 3;
  int br = g32 >> 4;
  const float* g1w = br ? g1w_w : g1w_h;
  __shared__ float gs[64][34];   // padded: col 0 and 33 zero
  int tid = threadIdx.x;
  const float* gb = g + (size_t)g32 * 8192 + cq*64*32;
  if (tid < 64) { gs[tid][0] = 0.f; gs[tid][33] = 0.f; }
  #pragma unroll
  for (int it = 0; it < 8; ++it) {
    int idx = it*256 + tid;
    gs[idx >> 5][1 + (idx & 31)] = gb[idx];
  }
  __syncthreads();
  int r = tid >> 2, l0 = (tid & 3) * 8;
  float acc[8];
  #pragma unroll
  for (int j = 0; j < 8; ++j) acc[j] = 0.f;
  for (int c = 0; c < 64; ++c) {
    const float* wp = g1w + (r*256 + cq*64 + c)*3;
    float w0 = wp[0], w1 = wp[1], w2 = wp[2];
    float gv[10];
    #pragma unroll
    for (int q = 0; q < 10; ++q) gv[q] = gs[c][l0 + q];
    #pragma unroll
    for (int j = 0; j < 8; ++j) acc[j] += w0*gv[j] + w1*gv[j+1] + w2*gv[j+2];
  }
  float* po = part + (size_t)blk*2048 + r*32 + l0;
  #pragma unroll
  for (int j = 0; j < 8; ++j) po[j] = acc[j];
}

// ---------------------------------------------------------------------------
// K1b: conv2 partial-channel blocks. grid 128 = (g32 = blk>>2, cq = blk&3).
__global__ __launch_bounds__(256) void k_gen2(const float* __restrict__ part,
    float* __restrict__ a2buf, float* __restrict__ sred,
    const float* bng_h, const float* bnb_h, const float* bnrm_h, const float* bnrv_h,
    const float* g2w_h, const float* bng_w, const float* bnb_w,
    const float* bnrm_w, const float* bnrv_w, const float* g2w_w)
{
  int blk = blockIdx.x; int g32 = blk >> 2, cq = blk & 3;
  int br = g32 >> 4;
  const float* bng  = br ? bng_w  : bng_h;
  const float* bnb  = br ? bnb_w  : bnb_h;
  const float* bnrm = br ? bnrm_w : bnrm_h;
  const float* bnrv = br ? bnrv_w : bnrv_h;
  const float* g2w  = br ? g2w_w  : g2w_h;

  __shared__ float h1[64][34];
  __shared__ float wlds[64*195];   // stride 195: 195%32=3 -> 16 cl conflict-free
  __shared__ float red[8];
  int tid = threadIdx.x;

  // (a) phase A: reduce 4 partials -> BN -> hardswish -> h1
  {
    int r = tid >> 2, l0 = (tid & 3) * 8;
    if ((tid & 3) == 0) { h1[r][0] = 0.f; h1[r][33] = 0.f; }
    const float* p0 = part + (size_t)(g32*4 + 0)*2048 + r*32 + l0;
    const float* p1 = part + (size_t)(g32*4 + 1)*2048 + r*32 + l0;
    const float* p2 = part + (size_t)(g32*4 + 2)*2048 + r*32 + l0;
    const float* p3 = part + (size_t)(g32*4 + 3)*2048 + r*32 + l0;
    float sc = bng[r] * rsqrtf(bnrv[r] + 1e-5f);
    float sh = bnb[r] - bnrm[r] * sc;
    #pragma unroll
    for (int j = 0; j < 8; ++j) {
      float v2 = (p0[j] + p1[j] + p2[j] + p3[j])*sc + sh;            // BN
      float hs = v2 * fminf(fmaxf(v2 + 3.f, 0.f), 6.f) * (1.f/6.f);  // hardswish
      h1[r][1 + l0 + j] = hs;
    }
  }
  // (b) stage g2w slice (c in [cq*64, cq*64+64)): 12288 contiguous floats
  {
    const float* wsrc = g2w + cq*12288;
    #pragma unroll
    for (int it = 0; it < 48; ++it) {
      int i = it*256 + tid;
      int cl = i / 192;
      int rem = i - cl*192;
      wlds[cl*195 + rem] = wsrc[i];
    }
  }
  __syncthreads();

  // (c) conv2: thread = (cl = tid>>2, l-octet = tid&3)
  int cl = tid >> 2, l0 = (tid & 3) * 8;
  const float* wp = &wlds[cl*195];
  float a2[8];
  #pragma unroll
  for (int j = 0; j < 8; ++j) a2[j] = 0.f;
  for (int r = 0; r < 64; ++r) {
    float w0 = wp[r*3+0], w1 = wp[r*3+1], w2 = wp[r*3+2];
    float hv[10];
    #pragma unroll
    for (int q = 0; q < 10; ++q) hv[q] = h1[r][l0 + q];
    #pragma unroll
    for (int j = 0; j < 8; ++j) a2[j] += w0*hv[j] + w1*hv[j+1] + w2*hv[j+2];
  }
  // (d) block partial moments + a2 out
  float s = 0.f, sq = 0.f;
  #pragma unroll
  for (int j = 0; j < 8; ++j) { s += a2[j]; sq += a2[j]*a2[j]; }
  #pragma unroll
  for (int off = 32; off >= 1; off >>= 1) { s += __shfl_xor(s, off); sq += __shfl_xor(sq, off); }
  if ((tid & 63) == 0) { red[(tid >> 6)*2] = s; red[(tid >> 6)*2+1] = sq; }
  __syncthreads();
  if (tid == 0) {
    sred[blk*2+0] = red[0] + red[2] + red[4] + red[6];
    sred[blk*2+1] = red[1] + red[3] + red[5] + red[7];
  }
  float* ao = a2buf + (size_t)(g32*256 + cq*64 + cl)*32 + l0;
  #pragma unroll
  for (int j = 0; j < 8; ++j) ao[j] = a2[j];
}

// ---------------------------------------------------------------------------
// K3: circulant apply per (b,ch) with INLINE filter-norm (absorbs k_gen3):
// ww[k] = (a2buf[g32,c,k]-u)*inv*fns[c,k]+fnm[c,k], u/inv from sred moments.
__global__ __launch_bounds__(256) void k_circ(const float* __restrict__ x,
    const float* __restrict__ pe_h, const float* __restrict__ pe_w,
    const float* __restrict__ bias_h, const float* __restrict__ bias_w,
    const float* __restrict__ a2buf, const float* __restrict__ sred,
    const float* __restrict__ fns_h, const float* __restrict__ fnm_h,
    const float* __restrict__ fns_w, const float* __restrict__ fnm_w,
    u16* __restrict__ ybr)
{
  int bc = blockIdx.x;
  int b = bc >> 9, ch = bc & 511, br = ch >> 8, c = ch & 255;
  __shared__ float xs[32][36];
  __shared__ float ww[32];
  int tid = threadIdx.x;
  const float* xp = x + (size_t)bc * 1024;
  float4 v = ((const float4*)xp)[tid];
  int h = tid >> 3, w4 = (tid & 7) * 4;
  if (br == 0) {
    float p = pe_h[c*32 + h];
    float4 sv; sv.x = v.x + p; sv.y = v.y + p; sv.z = v.z + p; sv.w = v.w + p;
    *(float4*)&xs[h][w4] = sv;
  } else {
    float4 pw = *(const float4*)(pe_w + c*32 + w4);
    float4 sv; sv.x = v.x + pw.x; sv.y = v.y + pw.y; sv.z = v.z + pw.z; sv.w = v.w + pw.w;
    *(float4*)&xs[h][w4] = sv;
  }
  if (tid < 32) {
    int g32v = br*BB + b;
    float S  = sred[g32v*8+0] + sred[g32v*8+2] + sred[g32v*8+4] + sred[g32v*8+6];
    float SQ = sred[g32v*8+1] + sred[g32v*8+3] + sred[g32v*8+5] + sred[g32v*8+7];
    float u   = S * (1.f/8192.f);
    float var = SQ * (1.f/8192.f) - u*u;
    float inv = rsqrtf(var + 1e-6f);
    const float* fns = br ? fns_w : fns_h;
    const float* fnm = br ? fnm_w : fnm_h;
    float av = a2buf[((size_t)g32v*256 + c)*32 + tid];
    ww[tid] = (av - u)*inv*fns[c*32 + tid] + fnm[c*32 + tid];
  }
  __syncthreads();
  float bias = (br ? bias_w : bias_h)[c];
  int i = tid >> 3;
  float o0 = bias, o1 = bias, o2 = bias, o3 = bias;
  if (br == 0) {
    #pragma unroll
    for (int k = 0; k < 32; ++k) {
      float wk = ww[k]; int rr = (i + k) & 31;
      float4 xv = *(const float4*)&xs[rr][w4];
      o0 += wk*xv.x; o1 += wk*xv.y; o2 += wk*xv.z; o3 += wk*xv.w;
    }
  } else {
    #pragma unroll
    for (int k = 0; k < 32; ++k) {
      float wk = ww[k];
      o0 += wk*xs[i][(w4+0+k) & 31]; o1 += wk*xs[i][(w4+1+k) & 31];
      o2 += wk*xs[i][(w4+2+k) & 31]; o3 += wk*xs[i][(w4+3+k) & 31];
    }
  }
  ushort4 o; o.x = f2bf(o0); o.y = f2bf(o1); o.z = f2bf(o2); o.w = f2bf(o3);
  ((ushort4*)(ybr + (size_t)bc * 1024))[tid] = o;
}

// ---------------------------------------------------------------------------
// K4: transpose (b,ch,h,w)->token-major + LayerNorm + fp8 pack. A8 [token][512].
__global__ __launch_bounds__(256) void k_ln(const u16* __restrict__ ybr,
    const float* __restrict__ ln_w, const float* __restrict__ ln_b,
    u8* __restrict__ A8)
{
  int bh = blockIdx.x; int b = bh >> 5, h = bh & 31;
  __shared__ float ys[512][33];
  __shared__ float ps[8][32], pq[8][32];
  __shared__ float mus[32], rstds[32];
  __shared__ float lw[512], lb[512];
  int tid = threadIdx.x;
  lw[tid]       = ln_w[tid];       lb[tid]       = ln_b[tid];
  lw[tid + 256] = ln_w[tid + 256]; lb[tid + 256] = ln_b[tid + 256];
  #pragma unroll
  for (int it = 0; it < 16; ++it) {
    int vid = it*256 + tid; int ch = vid >> 3; int w4 = (vid & 7) * 4;
    ushort4 v = *(const ushort4*)(ybr + (size_t)(b*512 + ch)*1024 + h*32 + w4);
    ys[ch][w4+0] = bf2f(v.x); ys[ch][w4+1] = bf2f(v.y);
    ys[ch][w4+2] = bf2f(v.z); ys[ch][w4+3] = bf2f(v.w);
  }
  __syncthreads();
  int w = tid & 31, gq = tid >> 5;
  float s = 0.f, sq = 0.f;
  for (int cc = gq*64; cc < gq*64 + 64; ++cc) { float vv = ys[cc][w]; s += vv; sq += vv*vv; }
  ps[gq][w] = s; pq[gq][w] = sq;
  __syncthreads();
  if (tid < 32) {
    float S = 0.f, SQ = 0.f;
    #pragma unroll
    for (int q = 0; q < 8; ++q) { S += ps[q][tid]; SQ += pq[q][tid]; }
    float mu = S * (1.f/512.f);
    float var = SQ * (1.f/512.f) - mu*mu;
    mus[tid] = mu; rstds[tid] = rsqrtf(var + 1e-6f);
  }
  __syncthreads();
  u8* Arow = A8 + (size_t)(b*1024 + h*32) * 512;
  #pragma unroll
  for (int it = 0; it < 16; ++it) {
    int idx = it*256 + tid;                 // 4096 dword groups
    int w2 = idx >> 7, cg = idx & 127; int cc = cg*4;
    float mu = mus[w2], rs2 = rstds[w2];
    float v0 = (ys[cc+0][w2] - mu) * rs2 * lw[cc+0] + lb[cc+0];
    float v1 = (ys[cc+1][w2] - mu) * rs2 * lw[cc+1] + lb[cc+1];
    float v2 = (ys[cc+2][w2] - mu) * rs2 * lw[cc+2] + lb[cc+2];
    float v3 = (ys[cc+3][w2] - mu) * rs2 * lw[cc+3] + lb[cc+3];
    ((unsigned int*)(Arow + (size_t)w2*512))[cg] = pk4_fp8(v0, v1, v2, v3);
  }
}

// ---------------------------------------------------------------------------
// K5/K6: fp8 MFMA GEMM (R13 core). 1-D grid with XCD-AWARE TEMPORAL SWIZZLE,
// derived from the ROUND-ROBIN dispatch model proven by R16/R17 counters
// (m-fast: 38.7MB fetch; n-fast: 86MB = A x 8 XCDs):
//   x = lin&7 (XCD), j = lin>>3 (temporal index on that XCD),
//   n = j%NB, m = (j/NB)*8 + x.
// -> same-A-panel blocks are (a) on ONE XCD and (b) temporally CONSECUTIVE,
// so each A/Z panel is fetched once and consumed L2-hot. Bijective when
// (grid%8==0 && Mblocks%8==0); guarded fallback to m-fast identity.
// Depth-2 prefetch, 3 LDS slots (48 KB, 3 blocks/CU). vmcnt(4)/(2)/(0).
// Chunk swizzle swz(r) = ((r>>1)^(r>>3))&3 on BOTH source and read.
// EPI=1: LDS-transpose epilogue + hard-sigmoid GELU. EPI=2: float4 residual.
template<int EPI, int NB>
__global__ __launch_bounds__(512, 6) void k_gemm(
    const u8* __restrict__ A, const u8* __restrict__ BT,
    void* __restrict__ outv, const float* __restrict__ xin,
    const float* __restrict__ bias, const float* __restrict__ gamma,
    int K, int N, int a_row_off, int out_row_off)
{
  __shared__ u8 As[3][8192];
  __shared__ u8 Bs[3][8192];
  int tid = threadIdx.x;
  int lin = blockIdx.x;
  int mblocks = gridDim.x / NB;
  int m0, n0;
  if ((gridDim.x & 7) == 0 && (mblocks & 7) == 0) {
    int xcd = lin & 7, j = lin >> 3;
    n0 = (j % NB) * 128;
    m0 = ((j / NB) * 8 + xcd) * 128;
  } else {
    m0 = (lin % mblocks) * 128;          // m-fast identity fallback
    n0 = (lin / mblocks) * 128;
  }
  int lane = tid & 63, wid = tid >> 6;
  int wr = wid >> 1, wc = wid & 1;          // wave tile: rows wr*32.., cols wc*64..
  f32x4 acc[2][4];
  #pragma unroll
  for (int mi = 0; mi < 2; ++mi)
    #pragma unroll
    for (int ni = 0; ni < 4; ++ni) acc[mi][ni] = (f32x4){0.f,0.f,0.f,0.f};

  // staging: tile = 128 rows x 64 B; wave u covers rows 16u..16u+15.
  // lane l -> row 16u + (l>>2), 16B chunk (l&3) ^ swz(row).
  int rloc = (wid << 4) + (lane >> 2);
  int swzr = ((rloc >> 1) ^ (rloc >> 3)) & 3;
  int cp   = (lane & 3) ^ swzr;
  const u8* aSrc = A  + (size_t)(a_row_off + m0 + rloc)*K + cp*16;
  const u8* bSrc = BT + (size_t)(n0 + rloc)*K + cp*16;
  int ldsOff = wid * 1024;                  // wave-uniform byte base

  auto stage = [&](int t, int slot) {
    int k0 = t << 6;
    gload16(aSrc + k0, &As[slot][ldsOff]);
    gload16(bSrc + k0, &Bs[slot][ldsOff]);
  };
  // b64 fragment read: logical bytes [row][kk + q*8 .. +8]
  auto lds8 = [&](const u8* base, int row, int kk, int q) -> long {
    int j = (kk >> 4) + (q >> 1);
    int sz = ((row >> 1) ^ (row >> 3)) & 3;
    int byte = row*64 + ((j ^ sz) << 4) + ((q & 1) << 3);
    return *(const long*)(base + byte);
  };

  int nt = K >> 6;
  stage(0, 0);                              // prologue: depth-2
  stage(1, 1);

  int sr = 0;                               // slot of tile t
  for (int t = 0; t < nt; ++t) {
    if (t + 2 < nt) {
      int sw = (sr == 0) ? 2 : sr - 1;      // (t+2)%3 == (t-1)%3
      stage(t + 2, sw);
      asm volatile("s_waitcnt vmcnt(4)" ::: "memory");   // tile t landed; t+1,t+2 in flight
    } else if (t + 1 < nt) {
      asm volatile("s_waitcnt vmcnt(2)" ::: "memory");   // tile t landed; t+1 in flight
    } else {
      asm volatile("s_waitcnt vmcnt(0)" ::: "memory");
    }
    __builtin_amdgcn_s_barrier();                        // tile t collectively valid
    const u8* Ar = &As[sr][0];
    const u8* Br = &Bs[sr][0];
    int q = lane >> 4;
    #pragma unroll
    for (int kk = 0; kk < 64; kk += 32) {
      long af[2], bfr[4];
      #pragma unroll
      for (int mi = 0; mi < 2; ++mi)
        af[mi] = lds8(Ar, wr*32 + mi*16 + (lane & 15), kk, q);
      #pragma unroll
      for (int ni = 0; ni < 4; ++ni)
        bfr[ni] = lds8(Br, wc*64 + ni*16 + (lane & 15), kk, q);
      #pragma unroll
      for (int mi = 0; mi < 2; ++mi)
        #pragma unroll
        for (int ni = 0; ni < 4; ++ni)
          acc[mi][ni] = __builtin_amdgcn_mfma_f32_16x16x32_fp8_fp8(af[mi], bfr[ni], acc[mi][ni], 0, 0, 0);
    }
    __builtin_amdgcn_s_barrier();   // protect the slot the next stage overwrites
    sr = (sr == 2) ? 0 : sr + 1;
  }

  // ---------------- epilogue ----------------
  // D layout: col = lane&15 (n), row = (lane>>4)*4 + r (m), per (mi,ni) frag.
  if (EPI == 1) {
    // LDS-transpose epilogue: wave region 32 rows x 64 cols, row stride 80B.
    __builtin_amdgcn_s_barrier();           // all waves done reading As/Bs
    u8* eb = &As[0][0] + wid * 2560;        // 8 waves x 2560B = 20KB <= 24KB
    #pragma unroll
    for (int mi = 0; mi < 2; ++mi) {
      #pragma unroll
      for (int ni = 0; ni < 4; ++ni) {
        int n = n0 + wc*64 + ni*16 + (lane & 15);
        float bn = bias[n];
        int col = ni*16 + (lane & 15);
        #pragma unroll
        for (int r = 0; r < 4; ++r) {
          int lrow = mi*16 + (lane >> 4)*4 + r;
          float v = acc[mi][ni][r] + bn;
          // hard-sigmoid GELU: v * clamp(0.2837v + 0.5, 0, 1)  (exp-free)
          float hs = fminf(fmaxf(0.2837f * v + 0.5f, 0.f), 1.f);
          eb[lrow*80 + col] = f2fp8(v * hs);
        }
      }
    }
    asm volatile("s_waitcnt lgkmcnt(0)" ::: "memory");  // own-region writes done
    int lr = lane >> 1, h2 = lane & 1;
    uint4 w0 = *(const uint4*)(eb + lr*80 + h2*32);
    uint4 w1 = *(const uint4*)(eb + lr*80 + h2*32 + 16);
    u8* zrow = (u8*)outv + (size_t)(m0 + wr*32 + lr)*N + n0 + wc*64 + h2*32;
    *(uint4*)(zrow)      = w0;
    *(uint4*)(zrow + 16) = w1;
  } else {
    #pragma unroll
    for (int mi = 0; mi < 2; ++mi) {
      #pragma unroll
      for (int ni = 0; ni < 4; ++ni) {
        int n = n0 + wc*64 + ni*16 + (lane & 15);
        float bn = bias[n];
        float gm = gamma[n];
        int mb = m0 + wr*32 + mi*16 + (lane >> 4)*4;    // 4-aligned token base
        int mg = out_row_off + mb;
        int bb = mg >> 10, hh = (mg >> 5) & 31, wv = mg & 31;
        size_t oi = ((size_t)(bb*512 + n))*1024 + hh*32 + wv;
        float4 xv = *(const float4*)(xin + oi);
        float4 ov;
        ov.x = xv.x + gm * (acc[mi][ni][0] + bn);
        ov.y = xv.y + gm * (acc[mi][ni][1] + bn);
        ov.z = xv.z + gm * (acc[mi][ni][2] + bn);
        ov.w = xv.w + gm * (acc[mi][ni][3] + bn);
        *(float4*)((float*)outv + oi) = ov;
      }
    }
  }
}

// ---------------------------------------------------------------------------
extern "C" void kernel_launch(void* const* d_in, const int* in_sizes, int n_in,
                              void* d_out, int out_size, void* d_ws, size_t ws_size,
                              hipStream_t stream)
{
  const float* x      = (const float*)d_in[0];
  const float* pe_h   = (const float*)d_in[1];
  const float* g1w_h  = (const float*)d_in[2];
  const float* bng_h  = (const float*)d_in[3];
  const float* bnb_h  = (const float*)d_in[4];
  const float* bnrm_h = (const float*)d_in[5];
  const float* bnrv_h = (const float*)d_in[6];
  const float* g2w_h  = (const float*)d_in[7];
  const float* fns_h  = (const float*)d_in[8];
  const float* fnm_h  = (const float*)d_in[9];
  const float* bias_h = (const float*)d_in[10];
  const float* pe_w   = (const float*)d_in[11];
  const float* g1w_w  = (const float*)d_in[12];
  const float* bng_w  = (const float*)d_in[13];
  const float* bnb_w  = (const float*)d_in[14];
  const float* bnrm_w = (const float*)d_in[15];
  const float* bnrv_w = (const float*)d_in[16];
  const float* g2w_w  = (const float*)d_in[17];
  const float* fns_w  = (const float*)d_in[18];
  const float* fnm_w  = (const float*)d_in[19];
  const float* bias_w = (const float*)d_in[20];
  const float* ln_w   = (const float*)d_in[21];
  const float* ln_b   = (const float*)d_in[22];
  const float* pw1w   = (const float*)d_in[23];
  const float* pw1b   = (const float*)d_in[24];
  const float* pw2w   = (const float*)d_in[25];
  const float* pw2b   = (const float*)d_in[26];
  const float* gamma  = (const float*)d_in[27];
  float* out = (float*)d_out;

  char* ws = (char*)d_ws;
  size_t off = 0;
  auto carve = [&](size_t bytes) -> void* {
    void* p = ws + off; off += (bytes + 255) & ~(size_t)255; return p;
  };
  float* g    = (float*)carve((size_t)2*BB*256*32*4);   // 1 MB
  float* part = (float*)carve((size_t)128*2048*4);      // 1 MB conv1 partials
  float* a2b  = (float*)carve((size_t)32*256*32*4);     // 1 MB conv2 pre-norm
  float* sred = (float*)carve((size_t)128*2*4);         // block moments
  u8* BT1     = (u8*)carve((size_t)2048*512);           // 1 MB fp8
  u8* BT2     = (u8*)carve((size_t)512*2048);           // 1 MB fp8
  u8* Abuf    = (u8*)carve((size_t)NTOK*512);           // 8.4 MB fp8
  size_t tail = off;                                    // ybr / Z share this region
  u16* ybr = (u16*)(ws + tail);
  u8*  Z   = (u8*)(ws + tail);                          // Z overwrites dead ybr
  size_t ybr_bytes = (size_t)NTOK*512*2;                // 16.8 MB
  int nch = 1;                                          // chunk M so Z fits in ws
  while (nch < 16) {
    size_t zb = ((size_t)NTOK/nch)*2048;                // fp8 Z
    size_t need = tail + (zb > ybr_bytes ? zb : ybr_bytes);
    if (need <= ws_size) break;
    nch *= 2;
  }

  k_pre<<<512 + BB*512, 256, 0, stream>>>(pw1w, BT1, pw2w, BT2, x, pe_h, pe_w, g);
  k_gen1<<<128, 256, 0, stream>>>(g, part, g1w_h, g1w_w);
  k_gen2<<<128, 256, 0, stream>>>(part, a2b, sred,
      bng_h, bnb_h, bnrm_h, bnrv_h, g2w_h,
      bng_w, bnb_w, bnrm_w, bnrv_w, g2w_w);
  k_circ<<<BB*512, 256, 0, stream>>>(x, pe_h, pe_w, bias_h, bias_w,
      a2b, sred, fns_h, fnm_h, fns_w, fnm_w, ybr);
  k_ln<<<BB*LL, 256, 0, stream>>>(ybr, ln_w, ln_b, Abuf);

  int Mc = NTOK / nch;
  for (int ci = 0; ci < nch; ++ci) {
    int moff = ci * Mc;
    k_gemm<1,16><<<(Mc/128)*16, 512, 0, stream>>>(
        Abuf, BT1, Z, nullptr, pw1b, nullptr, 512, 2048, moff, 0);
    k_gemm<2,4><<<(Mc/128)*4, 512, 0, stream>>>(
        Z, BT2, out, x, pw2b, gamma, 2048, 512, 0, moff);
  }
}